// Round 1
// baseline (636.694 us; speedup 1.0000x reference)
//
#include <hip/hip_runtime.h>
#include <math.h>

// ---------------------------------------------------------------------------
// VideoChat3 vision encoder block, bf16-MFMA pipeline.
// S=8192 tokens, H=1024, NH=16, HD=64, NSEG=8, L=1024, MLP=4096.
// Workspace layout (MB offsets):
//   0   hb    (S*H bf16, 16MB)      LN output / reused for LN1 output
//   16  bqkv  (3072*1024 bf16, 6MB)
//   22  bwo   (1024*1024 bf16, 2MB)
//   24  bfc0  (4096*1024 bf16, 8MB)
//   32  bfc1  (1024*4096 bf16, 8MB)
//   40  qh    (8,16,1024,64 bf16, 16MB)  rope'd q, pre-scaled 1/8
//   56  kh    (16MB)                     rope'd k
//   72  vt    (8,16,64,1024 bf16, 16MB)  v transposed
//   88  attnb (S*H bf16, 16MB)
//   104 qkvb  (S*3072 bf16, 48MB)  aliased with midb (S*MLP bf16, 64MB)
// total 168 MB
// ---------------------------------------------------------------------------

typedef __bf16 bf16x8 __attribute__((ext_vector_type(8)));
typedef float f32x4 __attribute__((ext_vector_type(4)));

__device__ __forceinline__ unsigned short f2b(float f) {  // RNE f32->bf16
  unsigned u = __float_as_uint(f);
  return (unsigned short)((u + 0x7FFFu + ((u >> 16) & 1u)) >> 16);
}
__device__ __forceinline__ float b2f(unsigned short h) {
  return __uint_as_float(((unsigned)h) << 16);
}
__device__ __forceinline__ void async_ld16(const void* g, void* l) {
  __builtin_amdgcn_global_load_lds((__attribute__((address_space(1))) void*)g,
                                   (__attribute__((address_space(3))) void*)l,
                                   16, 0, 0);
}

// ---------------- elementwise cast fp32 -> bf16 (float4 per thread) --------
__global__ __launch_bounds__(256) void castw_kernel(const float* __restrict__ src,
                                                    unsigned short* __restrict__ dst,
                                                    int n4) {
  int t = blockIdx.x * 256 + threadIdx.x;
  if (t >= n4) return;
  float4 v = ((const float4*)src)[t];
  ushort4 o;
  o.x = f2b(v.x); o.y = f2b(v.y); o.z = f2b(v.z); o.w = f2b(v.w);
  ((ushort4*)dst)[t] = o;
}

// ---------------- layernorm (row of 1024) -> bf16 --------------------------
__global__ __launch_bounds__(256) void ln_kernel(const float* __restrict__ x,
                                                 const float* __restrict__ g,
                                                 const float* __restrict__ bt,
                                                 unsigned short* __restrict__ out) {
  __shared__ float red[8];
  const int row = blockIdx.x, t = threadIdx.x;
  const float4 v = ((const float4*)(x + (size_t)row * 1024))[t];
  float s = v.x + v.y + v.z + v.w;
  float s2 = v.x * v.x + v.y * v.y + v.z * v.z + v.w * v.w;
#pragma unroll
  for (int m = 1; m < 64; m <<= 1) {
    s += __shfl_xor(s, m, 64);
    s2 += __shfl_xor(s2, m, 64);
  }
  if ((t & 63) == 0) { red[t >> 6] = s; red[4 + (t >> 6)] = s2; }
  __syncthreads();
  const float ts = red[0] + red[1] + red[2] + red[3];
  const float ts2 = red[4] + red[5] + red[6] + red[7];
  const float mean = ts * (1.f / 1024.f);
  const float var = ts2 * (1.f / 1024.f) - mean * mean;
  const float inv = rsqrtf(var + 1e-5f);
  const float4 gv = ((const float4*)g)[t];
  const float4 bv = ((const float4*)bt)[t];
  ushort4 o;
  o.x = f2b((v.x - mean) * inv * gv.x + bv.x);
  o.y = f2b((v.y - mean) * inv * gv.y + bv.y);
  o.z = f2b((v.z - mean) * inv * gv.z + bv.z);
  o.w = f2b((v.w - mean) * inv * gv.w + bv.w);
  ((ushort4*)out)[(size_t)row * 256 + t] = o;
}

// ---------------- GEMM: C[M,N] = A[M,K] @ B[N,K]^T, bf16 in, fp32 acc ------
// 128x128 tile, 4 waves (2x2 of 64x64), 16x16x32 MFMA, global_load_lds width16.
// MODE 1: outf = acc + res          (fp32)
// MODE 2: outb = bf16(gelu(acc + bias))
// MODE 3: outf = acc + bias + res   (fp32)
// MODE 4: outb = bf16(acc)
template <int MODE>
__global__ __launch_bounds__(256) void gemm_bt(
    const unsigned short* __restrict__ A, const unsigned short* __restrict__ B,
    int M, int N, int K, float* __restrict__ outf, unsigned short* __restrict__ outb,
    const float* __restrict__ res, const float* __restrict__ bias) {
  __shared__ __align__(16) unsigned short As[128 * 32];
  __shared__ __align__(16) unsigned short Bs[128 * 32];
  const int bm = blockIdx.y * 128, bn = blockIdx.x * 128;
  const int t = threadIdx.x, wave = t >> 6, lane = t & 63;
  const int quad = lane >> 4, l16 = lane & 15;
  const int wm = (wave >> 1) * 64, wn = (wave & 1) * 64;
  const int srow = lane >> 2, scol = (lane & 3) * 8;
  const unsigned short* Ag0 = A + (size_t)(bm + wave * 32 + srow) * K + scol;
  const unsigned short* Ag1 = Ag0 + (size_t)16 * K;
  const unsigned short* Bg0 = B + (size_t)(bn + wave * 32 + srow) * K + scol;
  const unsigned short* Bg1 = Bg0 + (size_t)16 * K;
  unsigned short* Al = As + wave * 1024;
  unsigned short* Bl = Bs + wave * 1024;
  f32x4 acc[4][4] = {};
  for (int k0 = 0; k0 < K; k0 += 32) {
    async_ld16(Ag0 + k0, Al);
    async_ld16(Ag1 + k0, Al + 512);
    async_ld16(Bg0 + k0, Bl);
    async_ld16(Bg1 + k0, Bl + 512);
    __syncthreads();
    bf16x8 af[4], bfv[4];
#pragma unroll
    for (int i = 0; i < 4; i++)
      af[i] = *(const bf16x8*)(As + (wm + i * 16 + l16) * 32 + quad * 8);
#pragma unroll
    for (int j = 0; j < 4; j++)
      bfv[j] = *(const bf16x8*)(Bs + (wn + j * 16 + l16) * 32 + quad * 8);
#pragma unroll
    for (int i = 0; i < 4; i++)
#pragma unroll
      for (int j = 0; j < 4; j++)
        acc[i][j] = __builtin_amdgcn_mfma_f32_16x16x32_bf16(af[i], bfv[j], acc[i][j], 0, 0, 0);
    __syncthreads();
  }
#pragma unroll
  for (int i = 0; i < 4; i++)
#pragma unroll
    for (int j = 0; j < 4; j++)
#pragma unroll
      for (int r = 0; r < 4; r++) {
        const int m = bm + wm + i * 16 + quad * 4 + r;
        const int n = bn + wn + j * 16 + l16;
        const size_t idx = (size_t)m * N + n;
        const float v = acc[i][j][r];
        if (MODE == 1) {
          outf[idx] = v + res[idx];
        } else if (MODE == 2) {
          const float z = v + bias[n];
          outb[idx] = f2b(0.5f * z * (1.f + erff(z * 0.70710678f)));
        } else if (MODE == 3) {
          outf[idx] = v + bias[n] + res[idx];
        } else {  // MODE 4
          outb[idx] = f2b(v);
        }
      }
}

// ---------------- RoPE: qkv(bf16,[S,3,NH,HD]) -> qh,kh ([seg,NH,L,HD]) -----
__global__ __launch_bounds__(256) void rope_kernel(const unsigned short* __restrict__ qkv,
                                                   const float* __restrict__ cb,
                                                   const float* __restrict__ sb,
                                                   unsigned short* __restrict__ qh,
                                                   unsigned short* __restrict__ kh) {
  const int tid = blockIdx.x * 256 + threadIdx.x;  // S*NH*32 threads
  const int i = tid & 31, head = (tid >> 5) & 15, s = tid >> 9;
  const float c = cb[s * 32 + i], sn = sb[s * 32 + i];
  const unsigned short* base = qkv + (size_t)s * 3072 + head * 64 + 2 * i;
  const float q0 = b2f(base[0]), q1 = b2f(base[1]);
  const float k0 = b2f(base[1024]), k1 = b2f(base[1025]);
  const int seg = s >> 10, l = s & 1023;
  const size_t o = ((size_t)((seg * 16 + head) * 1024 + l)) * 64 + 2 * i;
  ushort2 qo, ko;
  qo.x = f2b((q0 * c - q1 * sn) * 0.125f);  // fold 1/sqrt(HD) into q
  qo.y = f2b((q0 * sn + q1 * c) * 0.125f);
  ko.x = f2b(k0 * c - k1 * sn);
  ko.y = f2b(k0 * sn + k1 * c);
  *(ushort2*)(qh + o) = qo;
  *(ushort2*)(kh + o) = ko;
}

// ---------------- V transpose: qkv v-part -> vt [seg,NH,HD,L] --------------
__global__ __launch_bounds__(256) void vtrans_kernel(const unsigned short* __restrict__ qkv,
                                                     unsigned short* __restrict__ vt) {
  __shared__ unsigned short tile[64][72];
  const int b = blockIdx.x;  // 8*16*16
  const int lt = b & 15, head = (b >> 4) & 15, seg = b >> 8;
  const int t = threadIdx.x;
  const int r = t >> 2, c0 = (t & 3) * 16;
  const unsigned short* src =
      qkv + ((size_t)(seg * 1024 + lt * 64 + r)) * 3072 + 2048 + head * 64 + c0;
#pragma unroll
  for (int k = 0; k < 16; k++) tile[r][c0 + k] = src[k];
  __syncthreads();
  unsigned short* dst =
      vt + ((size_t)((seg * 16 + head) * 64 + r)) * 1024 + lt * 64 + c0;
#pragma unroll
  for (int k = 0; k < 16; k++) dst[k] = tile[c0 + k][r];
}

// ---------------- flash attention: per (seg, head, 128-row q tile) ---------
__global__ __launch_bounds__(256) void attn_kernel(const unsigned short* __restrict__ qh,
                                                   const unsigned short* __restrict__ kh,
                                                   const unsigned short* __restrict__ vt,
                                                   unsigned short* __restrict__ out) {
  __shared__ __align__(16) unsigned short Qs[128 * 64];
  __shared__ __align__(16) unsigned short Ks[64 * 64];
  __shared__ __align__(16) unsigned short Vs[64 * 64];  // [hd][key]
  __shared__ __align__(16) unsigned short Ps[128 * 72];
  const int b = blockIdx.x;
  const int qt = b & 7, head = (b >> 3) & 15, seg = b >> 7;
  const int t = threadIdx.x, wave = t >> 6, lane = t & 63;
  const int quad = lane >> 4, l16 = lane & 15;
  const size_t sh = (size_t)(seg * 16 + head);
  const unsigned short* qbase = qh + (sh * 1024 + (size_t)qt * 128) * 64;
  const unsigned short* kbase = kh + sh * 1024 * 64;
  const unsigned short* vbase = vt + sh * 64 * 1024;
  const int r8 = lane >> 3, c8 = (lane & 7) * 8;
#pragma unroll
  for (int cc = 0; cc < 4; cc++) {  // stage Q once (16KB, 16 chunks)
    const int chunk = wave * 4 + cc;
    async_ld16(qbase + (size_t)(chunk * 8 + r8) * 64 + c8, Qs + chunk * 512);
  }
  float m_i[2][4], l_i[2][4];
  f32x4 o_acc[2][4] = {};
#pragma unroll
  for (int i = 0; i < 2; i++)
#pragma unroll
    for (int r = 0; r < 4; r++) { m_i[i][r] = -1e30f; l_i[i][r] = 0.f; }

  for (int kt = 0; kt < 16; kt++) {
    const int ch0 = wave * 2;
    async_ld16(kbase + (size_t)(kt * 64 + ch0 * 8 + r8) * 64 + c8, Ks + ch0 * 512);
    async_ld16(kbase + (size_t)(kt * 64 + ch0 * 8 + 8 + r8) * 64 + c8, Ks + ch0 * 512 + 512);
    async_ld16(vbase + (size_t)(ch0 * 8 + r8) * 1024 + kt * 64 + c8, Vs + ch0 * 512);
    async_ld16(vbase + (size_t)(ch0 * 8 + 8 + r8) * 1024 + kt * 64 + c8, Vs + ch0 * 512 + 512);
    __syncthreads();
    // S = Q K^T  (q pre-scaled by 1/8)
    f32x4 s[2][4] = {};
#pragma unroll
    for (int ks = 0; ks < 2; ks++) {
      bf16x8 aq[2], bk[4];
#pragma unroll
      for (int i = 0; i < 2; i++)
        aq[i] = *(const bf16x8*)(Qs + (wave * 32 + i * 16 + l16) * 64 + ks * 32 + quad * 8);
#pragma unroll
      for (int j = 0; j < 4; j++)
        bk[j] = *(const bf16x8*)(Ks + (j * 16 + l16) * 64 + ks * 32 + quad * 8);
#pragma unroll
      for (int i = 0; i < 2; i++)
#pragma unroll
        for (int j = 0; j < 4; j++)
          s[i][j] = __builtin_amdgcn_mfma_f32_16x16x32_bf16(aq[i], bk[j], s[i][j], 0, 0, 0);
    }
    // online softmax per row (row = quad*4+r within 16-tile)
#pragma unroll
    for (int i = 0; i < 2; i++)
#pragma unroll
      for (int r = 0; r < 4; r++) {
        float mx = fmaxf(fmaxf(s[i][0][r], s[i][1][r]), fmaxf(s[i][2][r], s[i][3][r]));
#pragma unroll
        for (int msk = 1; msk < 16; msk <<= 1) mx = fmaxf(mx, __shfl_xor(mx, msk, 64));
        const float mnew = fmaxf(m_i[i][r], mx);
        const float alpha = __expf(m_i[i][r] - mnew);
        const float p0 = __expf(s[i][0][r] - mnew);
        const float p1 = __expf(s[i][1][r] - mnew);
        const float p2 = __expf(s[i][2][r] - mnew);
        const float p3 = __expf(s[i][3][r] - mnew);
        float rs = p0 + p1 + p2 + p3;
#pragma unroll
        for (int msk = 1; msk < 16; msk <<= 1) rs += __shfl_xor(rs, msk, 64);
        l_i[i][r] = l_i[i][r] * alpha + rs;
        m_i[i][r] = mnew;
        const int prow = wave * 32 + i * 16 + quad * 4 + r;
        Ps[prow * 72 + 0 + l16] = f2b(p0);
        Ps[prow * 72 + 16 + l16] = f2b(p1);
        Ps[prow * 72 + 32 + l16] = f2b(p2);
        Ps[prow * 72 + 48 + l16] = f2b(p3);
#pragma unroll
        for (int j = 0; j < 4; j++) o_acc[i][j][r] *= alpha;
      }
    // O += P V   (A-frags from own wave's Ps rows; B-frags from Vs[hd][key])
#pragma unroll
    for (int ks = 0; ks < 2; ks++) {
      bf16x8 bv[4];
#pragma unroll
      for (int j = 0; j < 4; j++)
        bv[j] = *(const bf16x8*)(Vs + (j * 16 + l16) * 64 + ks * 32 + quad * 8);
#pragma unroll
      for (int i = 0; i < 2; i++) {
        const bf16x8 ap =
            *(const bf16x8*)(Ps + (wave * 32 + i * 16 + l16) * 72 + ks * 32 + quad * 8);
#pragma unroll
        for (int j = 0; j < 4; j++)
          o_acc[i][j] = __builtin_amdgcn_mfma_f32_16x16x32_bf16(ap, bv[j], o_acc[i][j], 0, 0, 0);
      }
    }
    __syncthreads();
  }
#pragma unroll
  for (int i = 0; i < 2; i++)
#pragma unroll
    for (int r = 0; r < 4; r++) {
      const float invl = 1.0f / l_i[i][r];
      const int qrow = seg * 1024 + qt * 128 + wave * 32 + i * 16 + quad * 4 + r;
#pragma unroll
      for (int j = 0; j < 4; j++)
        out[(size_t)qrow * 1024 + head * 64 + j * 16 + l16] = f2b(o_acc[i][j][r] * invl);
    }
}

// ---------------------------------------------------------------------------
extern "C" void kernel_launch(void* const* d_in, const int* in_sizes, int n_in,
                              void* d_out, int out_size, void* d_ws, size_t ws_size,
                              hipStream_t stream) {
  (void)in_sizes; (void)n_in; (void)out_size; (void)ws_size;
  const float* x    = (const float*)d_in[0];
  const float* wqkv = (const float*)d_in[1];
  const float* wo   = (const float*)d_in[2];
  const float* ln0g = (const float*)d_in[3];
  const float* ln0b = (const float*)d_in[4];
  const float* ln1g = (const float*)d_in[5];
  const float* ln1b = (const float*)d_in[6];
  const float* fc0w = (const float*)d_in[7];
  const float* fc0b = (const float*)d_in[8];
  const float* fc1w = (const float*)d_in[9];
  const float* fc1b = (const float*)d_in[10];
  const float* rc   = (const float*)d_in[11];
  const float* rsn  = (const float*)d_in[12];
  float* out = (float*)d_out;
  char* w = (char*)d_ws;
  const size_t MB = 1u << 20;
  unsigned short* hb    = (unsigned short*)(w + 0);
  unsigned short* bqkv  = (unsigned short*)(w + 16 * MB);
  unsigned short* bwo   = (unsigned short*)(w + 22 * MB);
  unsigned short* bfc0  = (unsigned short*)(w + 24 * MB);
  unsigned short* bfc1  = (unsigned short*)(w + 32 * MB);
  unsigned short* qhb   = (unsigned short*)(w + 40 * MB);
  unsigned short* khb   = (unsigned short*)(w + 56 * MB);
  unsigned short* vtb   = (unsigned short*)(w + 72 * MB);
  unsigned short* attnb = (unsigned short*)(w + 88 * MB);
  unsigned short* qkvb  = (unsigned short*)(w + 104 * MB);
  unsigned short* midb  = (unsigned short*)(w + 104 * MB);  // alias, qkvb dead by then

  castw_kernel<<<3072, 256, 0, stream>>>(wqkv, bqkv, 786432);
  castw_kernel<<<1024, 256, 0, stream>>>(wo, bwo, 262144);
  castw_kernel<<<4096, 256, 0, stream>>>(fc0w, bfc0, 1048576);
  castw_kernel<<<4096, 256, 0, stream>>>(fc1w, bfc1, 1048576);
  ln_kernel<<<8192, 256, 0, stream>>>(x, ln0g, ln0b, hb);
  gemm_bt<4><<<dim3(24, 64), 256, 0, stream>>>(hb, bqkv, 8192, 3072, 1024,
                                               nullptr, qkvb, nullptr, nullptr);
  rope_kernel<<<16384, 256, 0, stream>>>(qkvb, rc, rsn, qhb, khb);
  vtrans_kernel<<<2048, 256, 0, stream>>>(qkvb, vtb);
  attn_kernel<<<1024, 256, 0, stream>>>(qhb, khb, vtb, attnb);
  gemm_bt<1><<<dim3(8, 64), 256, 0, stream>>>(attnb, bwo, 8192, 1024, 1024,
                                              out, nullptr, x, nullptr);
  ln_kernel<<<8192, 256, 0, stream>>>(out, ln1g, ln1b, hb);
  gemm_bt<2><<<dim3(32, 64), 256, 0, stream>>>(hb, bfc0, 8192, 4096, 1024,
                                               nullptr, midb, nullptr, fc0b);
  gemm_bt<3><<<dim3(8, 64), 256, 0, stream>>>(midb, bfc1, 8192, 1024, 4096,
                                              out, nullptr, out, fc1b);
}

// Round 2
// 562.934 us; speedup vs baseline: 1.1310x; 1.1310x over previous
//
#include <hip/hip_runtime.h>
#include <math.h>

// ---------------------------------------------------------------------------
// VideoChat3 vision encoder block, bf16-MFMA pipeline. Round 2:
//  - XOR-swizzled LDS layouts (conflict-free ds_read_b128) in GEMM + attention
//  - max-free softmax: p = exp2(q.k * log2e / 8), log2e folded into q prescale
//  - attention block remap for XCD L2 affinity (head in low bits)
// S=8192, H=1024, NH=16, HD=64, NSEG=8, L=1024, MLP=4096.
// ---------------------------------------------------------------------------

typedef __bf16 bf16x8 __attribute__((ext_vector_type(8)));
typedef float f32x4 __attribute__((ext_vector_type(4)));

__device__ __forceinline__ unsigned short f2b(float f) {  // RNE f32->bf16
  unsigned u = __float_as_uint(f);
  return (unsigned short)((u + 0x7FFFu + ((u >> 16) & 1u)) >> 16);
}
__device__ __forceinline__ float b2f(unsigned short h) {
  return __uint_as_float(((unsigned)h) << 16);
}
__device__ __forceinline__ void async_ld16(const void* g, void* l) {
  __builtin_amdgcn_global_load_lds((__attribute__((address_space(1))) void*)g,
                                   (__attribute__((address_space(3))) void*)l,
                                   16, 0, 0);
}
__device__ __forceinline__ float exp2fast(float x) {
#if __has_builtin(__builtin_amdgcn_exp2f)
  return __builtin_amdgcn_exp2f(x);
#else
  return exp2f(x);
#endif
}

// ---------------- elementwise cast fp32 -> bf16 (float4 per thread) --------
__global__ __launch_bounds__(256) void castw_kernel(const float* __restrict__ src,
                                                    unsigned short* __restrict__ dst,
                                                    int n4) {
  int t = blockIdx.x * 256 + threadIdx.x;
  if (t >= n4) return;
  float4 v = ((const float4*)src)[t];
  ushort4 o;
  o.x = f2b(v.x); o.y = f2b(v.y); o.z = f2b(v.z); o.w = f2b(v.w);
  ((ushort4*)dst)[t] = o;
}

// ---------------- layernorm (row of 1024) -> bf16 --------------------------
__global__ __launch_bounds__(256) void ln_kernel(const float* __restrict__ x,
                                                 const float* __restrict__ g,
                                                 const float* __restrict__ bt,
                                                 unsigned short* __restrict__ out) {
  __shared__ float red[8];
  const int row = blockIdx.x, t = threadIdx.x;
  const float4 v = ((const float4*)(x + (size_t)row * 1024))[t];
  float s = v.x + v.y + v.z + v.w;
  float s2 = v.x * v.x + v.y * v.y + v.z * v.z + v.w * v.w;
#pragma unroll
  for (int m = 1; m < 64; m <<= 1) {
    s += __shfl_xor(s, m, 64);
    s2 += __shfl_xor(s2, m, 64);
  }
  if ((t & 63) == 0) { red[t >> 6] = s; red[4 + (t >> 6)] = s2; }
  __syncthreads();
  const float ts = red[0] + red[1] + red[2] + red[3];
  const float ts2 = red[4] + red[5] + red[6] + red[7];
  const float mean = ts * (1.f / 1024.f);
  const float var = ts2 * (1.f / 1024.f) - mean * mean;
  const float inv = rsqrtf(var + 1e-5f);
  const float4 gv = ((const float4*)g)[t];
  const float4 bv = ((const float4*)bt)[t];
  ushort4 o;
  o.x = f2b((v.x - mean) * inv * gv.x + bv.x);
  o.y = f2b((v.y - mean) * inv * gv.y + bv.y);
  o.z = f2b((v.z - mean) * inv * gv.z + bv.z);
  o.w = f2b((v.w - mean) * inv * gv.w + bv.w);
  ((ushort4*)out)[(size_t)row * 256 + t] = o;
}

// ---------------- GEMM: C[M,N] = A[M,K] @ B[N,K]^T, bf16 in, fp32 acc ------
// 128x128 tile, 4 waves (2x2 of 64x64), 16x16x32 MFMA, global_load_lds w16.
// LDS rows of 32 shorts, chunk slot c' holds logical chunk c^( (row>>1)&3 )
// -> ds_read_b128 lands 2-way on banks (free) instead of 8-way.
template <int MODE>
__global__ __launch_bounds__(256) void gemm_bt(
    const unsigned short* __restrict__ A, const unsigned short* __restrict__ B,
    int M, int N, int K, float* __restrict__ outf, unsigned short* __restrict__ outb,
    const float* __restrict__ res, const float* __restrict__ bias) {
  __shared__ __align__(16) unsigned short As[128 * 32];
  __shared__ __align__(16) unsigned short Bs[128 * 32];
  const int bm = blockIdx.y * 128, bn = blockIdx.x * 128;
  const int t = threadIdx.x, wave = t >> 6, lane = t & 63;
  const int quad = lane >> 4, l16 = lane & 15;
  const int wm = (wave >> 1) * 64, wn = (wave & 1) * 64;
  const int srow = lane >> 2;
  const int scol = (((lane & 3) ^ ((lane >> 3) & 3)) * 8);  // swizzled source col
  const unsigned short* Ag0 = A + (size_t)(bm + wave * 32 + srow) * K + scol;
  const unsigned short* Ag1 = Ag0 + (size_t)16 * K;
  const unsigned short* Bg0 = B + (size_t)(bn + wave * 32 + srow) * K + scol;
  const unsigned short* Bg1 = Bg0 + (size_t)16 * K;
  unsigned short* Al = As + wave * 1024;
  unsigned short* Bl = Bs + wave * 1024;
  const int swg = (l16 >> 1) & 3;  // read-side swizzle key
  f32x4 acc[4][4] = {};
  for (int k0 = 0; k0 < K; k0 += 32) {
    async_ld16(Ag0 + k0, Al);
    async_ld16(Ag1 + k0, Al + 512);
    async_ld16(Bg0 + k0, Bl);
    async_ld16(Bg1 + k0, Bl + 512);
    __syncthreads();
    bf16x8 af[4], bfv[4];
#pragma unroll
    for (int i = 0; i < 4; i++)
      af[i] = *(const bf16x8*)(As + (wm + i * 16 + l16) * 32 + (quad ^ swg) * 8);
#pragma unroll
    for (int j = 0; j < 4; j++)
      bfv[j] = *(const bf16x8*)(Bs + (wn + j * 16 + l16) * 32 + (quad ^ swg) * 8);
#pragma unroll
    for (int i = 0; i < 4; i++)
#pragma unroll
      for (int j = 0; j < 4; j++)
        acc[i][j] = __builtin_amdgcn_mfma_f32_16x16x32_bf16(af[i], bfv[j], acc[i][j], 0, 0, 0);
    __syncthreads();
  }
#pragma unroll
  for (int i = 0; i < 4; i++)
#pragma unroll
    for (int j = 0; j < 4; j++)
#pragma unroll
      for (int r = 0; r < 4; r++) {
        const int m = bm + wm + i * 16 + quad * 4 + r;
        const int n = bn + wn + j * 16 + l16;
        const size_t idx = (size_t)m * N + n;
        const float v = acc[i][j][r];
        if (MODE == 1) {
          outf[idx] = v + res[idx];
        } else if (MODE == 2) {
          const float z = v + bias[n];
          outb[idx] = f2b(0.5f * z * (1.f + erff(z * 0.70710678f)));
        } else if (MODE == 3) {
          outf[idx] = v + bias[n] + res[idx];
        } else {  // MODE 4
          outb[idx] = f2b(v);
        }
      }
}

// ---------------- RoPE: qkv(bf16,[S,3,NH,HD]) -> qh,kh ([seg,NH,L,HD]) -----
// q pre-scale folds 1/sqrt(HD) AND log2(e) so attention can use native exp2.
__global__ __launch_bounds__(256) void rope_kernel(const unsigned short* __restrict__ qkv,
                                                   const float* __restrict__ cb,
                                                   const float* __restrict__ sb,
                                                   unsigned short* __restrict__ qh,
                                                   unsigned short* __restrict__ kh) {
  const int tid = blockIdx.x * 256 + threadIdx.x;  // S*NH*32 threads
  const int i = tid & 31, head = (tid >> 5) & 15, s = tid >> 9;
  const float c = cb[s * 32 + i], sn = sb[s * 32 + i];
  const unsigned short* base = qkv + (size_t)s * 3072 + head * 64 + 2 * i;
  const float q0 = b2f(base[0]), q1 = b2f(base[1]);
  const float k0 = b2f(base[1024]), k1 = b2f(base[1025]);
  const int seg = s >> 10, l = s & 1023;
  const size_t o = ((size_t)((seg * 16 + head) * 1024 + l)) * 64 + 2 * i;
  const float QSC = 0.125f * 1.44269504f;
  ushort2 qo, ko;
  qo.x = f2b((q0 * c - q1 * sn) * QSC);
  qo.y = f2b((q0 * sn + q1 * c) * QSC);
  ko.x = f2b(k0 * c - k1 * sn);
  ko.y = f2b(k0 * sn + k1 * c);
  *(ushort2*)(qh + o) = qo;
  *(ushort2*)(kh + o) = ko;
}

// ---------------- V transpose: qkv v-part -> vt [seg,NH,HD,L] --------------
__global__ __launch_bounds__(256) void vtrans_kernel(const unsigned short* __restrict__ qkv,
                                                     unsigned short* __restrict__ vt) {
  __shared__ unsigned short tile[64][72];
  const int b = blockIdx.x;  // 8*16*16
  const int lt = b & 15, head = (b >> 4) & 15, seg = b >> 8;
  const int t = threadIdx.x;
  const int r = t >> 2, c0 = (t & 3) * 16;
  const unsigned short* src =
      qkv + ((size_t)(seg * 1024 + lt * 64 + r)) * 3072 + 2048 + head * 64 + c0;
#pragma unroll
  for (int k = 0; k < 16; k++) tile[r][c0 + k] = src[k];
  __syncthreads();
  unsigned short* dst =
      vt + ((size_t)((seg * 16 + head) * 64 + r)) * 1024 + lt * 64 + c0;
#pragma unroll
  for (int k = 0; k < 16; k++) dst[k] = tile[c0 + k][r];
}

// ---------------- flash attention (max-free softmax), per (head,seg,qtile) -
// Q/K/V LDS rows = 64 shorts with XOR chunk swizzle: slot c' at row r holds
// logical chunk c'^(r&7) -> 2-way banks on ds_read_b128 (free).
// P: stride 68 shorts -> 2-way on both b16 writes and b128 reads.
__global__ __launch_bounds__(256) void attn_kernel(const unsigned short* __restrict__ qh,
                                                   const unsigned short* __restrict__ kh,
                                                   const unsigned short* __restrict__ vt,
                                                   unsigned short* __restrict__ out) {
  __shared__ __align__(16) unsigned short Qs[128 * 64];
  __shared__ __align__(16) unsigned short Ks[64 * 64];
  __shared__ __align__(16) unsigned short Vs[64 * 64];  // [hd][key]
  __shared__ __align__(16) __bf16 Ps[128 * 68];
  const int b = blockIdx.x;
  // head in low 4 bits: XCD (= blk%8 round-robin) keeps reusing same heads' K/V
  const int head = b & 15, seg = (b >> 4) & 7, qt = b >> 7;
  const int t = threadIdx.x, wave = t >> 6, lane = t & 63;
  const int quad = lane >> 4, l16 = lane & 15;
  const size_t sh = (size_t)(seg * 16 + head);
  const unsigned short* qbase = qh + (sh * 1024 + (size_t)qt * 128) * 64;
  const unsigned short* kbase = kh + sh * 1024 * 64;
  const unsigned short* vbase = vt + sh * 64 * 1024;
  const int r8 = lane >> 3;
  const int c8 = ((lane & 7) ^ (r8 & 7)) * 8;  // swizzled source col (shorts)
#pragma unroll
  for (int cc = 0; cc < 4; cc++) {  // stage Q once (16KB, 16 chunks)
    const int chunk = wave * 4 + cc;
    async_ld16(qbase + (size_t)(chunk * 8 + r8) * 64 + c8, Qs + chunk * 512);
  }
  float lsum[2][4] = {};
  f32x4 o_acc[2][4] = {};
  const int sw = l16 & 7;  // read-side swizzle key (row ≡ l16 mod 16)

  for (int kt = 0; kt < 16; kt++) {
    const int ch0 = wave * 2;
    async_ld16(kbase + (size_t)(kt * 64 + ch0 * 8 + r8) * 64 + c8, Ks + ch0 * 512);
    async_ld16(kbase + (size_t)(kt * 64 + ch0 * 8 + 8 + r8) * 64 + c8, Ks + ch0 * 512 + 512);
    async_ld16(vbase + (size_t)(ch0 * 8 + r8) * 1024 + kt * 64 + c8, Vs + ch0 * 512);
    async_ld16(vbase + (size_t)(ch0 * 8 + 8 + r8) * 1024 + kt * 64 + c8, Vs + ch0 * 512 + 512);
    __syncthreads();
    // S = Q K^T  (q pre-scaled by log2e/8)
    f32x4 s[2][4] = {};
#pragma unroll
    for (int ks = 0; ks < 2; ks++) {
      const int co = ((ks * 4 + quad) ^ sw) * 8;
      bf16x8 aq[2], bk[4];
#pragma unroll
      for (int i = 0; i < 2; i++)
        aq[i] = *(const bf16x8*)(Qs + (wave * 32 + i * 16 + l16) * 64 + co);
#pragma unroll
      for (int j = 0; j < 4; j++)
        bk[j] = *(const bf16x8*)(Ks + (j * 16 + l16) * 64 + co);
#pragma unroll
      for (int i = 0; i < 2; i++)
#pragma unroll
        for (int j = 0; j < 4; j++)
          s[i][j] = __builtin_amdgcn_mfma_f32_16x16x32_bf16(aq[i], bk[j], s[i][j], 0, 0, 0);
    }
    // max-free softmax: p = exp2(s); row-sum deferred to epilogue
#pragma unroll
    for (int i = 0; i < 2; i++)
#pragma unroll
      for (int r = 0; r < 4; r++) {
        const float p0 = exp2fast(s[i][0][r]);
        const float p1 = exp2fast(s[i][1][r]);
        const float p2 = exp2fast(s[i][2][r]);
        const float p3 = exp2fast(s[i][3][r]);
        lsum[i][r] += (p0 + p1) + (p2 + p3);
        const int prow = wave * 32 + i * 16 + quad * 4 + r;
        __bf16* pb = Ps + prow * 68 + l16;
        pb[0]  = (__bf16)p0;
        pb[16] = (__bf16)p1;
        pb[32] = (__bf16)p2;
        pb[48] = (__bf16)p3;
      }
    // O += P V  (same-wave LDS RAW: in-order LDS pipe, no barrier needed)
#pragma unroll
    for (int ks = 0; ks < 2; ks++) {
      const int co = ((ks * 4 + quad) ^ sw) * 8;
      bf16x8 bv[4];
#pragma unroll
      for (int j = 0; j < 4; j++)
        bv[j] = *(const bf16x8*)(Vs + (j * 16 + l16) * 64 + co);
#pragma unroll
      for (int i = 0; i < 2; i++) {
        const bf16x8 ap = *(const bf16x8*)(Ps + (wave * 32 + i * 16 + l16) * 68 + ks * 32 + quad * 8);
#pragma unroll
        for (int j = 0; j < 4; j++)
          o_acc[i][j] = __builtin_amdgcn_mfma_f32_16x16x32_bf16(ap, bv[j], o_acc[i][j], 0, 0, 0);
      }
    }
    __syncthreads();
  }
#pragma unroll
  for (int i = 0; i < 2; i++)
#pragma unroll
    for (int r = 0; r < 4; r++) {
      float l = lsum[i][r];  // reduce across the 16 column-lanes, once
      l += __shfl_xor(l, 1, 64);
      l += __shfl_xor(l, 2, 64);
      l += __shfl_xor(l, 4, 64);
      l += __shfl_xor(l, 8, 64);
      const float invl = 1.0f / l;
      const int qrow = seg * 1024 + qt * 128 + wave * 32 + i * 16 + quad * 4 + r;
#pragma unroll
      for (int j = 0; j < 4; j++)
        out[(size_t)qrow * 1024 + head * 64 + j * 16 + l16] = f2b(o_acc[i][j][r] * invl);
    }
}

// ---------------------------------------------------------------------------
extern "C" void kernel_launch(void* const* d_in, const int* in_sizes, int n_in,
                              void* d_out, int out_size, void* d_ws, size_t ws_size,
                              hipStream_t stream) {
  (void)in_sizes; (void)n_in; (void)out_size; (void)ws_size;
  const float* x    = (const float*)d_in[0];
  const float* wqkv = (const float*)d_in[1];
  const float* wo   = (const float*)d_in[2];
  const float* ln0g = (const float*)d_in[3];
  const float* ln0b = (const float*)d_in[4];
  const float* ln1g = (const float*)d_in[5];
  const float* ln1b = (const float*)d_in[6];
  const float* fc0w = (const float*)d_in[7];
  const float* fc0b = (const float*)d_in[8];
  const float* fc1w = (const float*)d_in[9];
  const float* fc1b = (const float*)d_in[10];
  const float* rc   = (const float*)d_in[11];
  const float* rsn  = (const float*)d_in[12];
  float* out = (float*)d_out;
  char* w = (char*)d_ws;
  const size_t MB = 1u << 20;
  unsigned short* hb    = (unsigned short*)(w + 0);
  unsigned short* bqkv  = (unsigned short*)(w + 16 * MB);
  unsigned short* bwo   = (unsigned short*)(w + 22 * MB);
  unsigned short* bfc0  = (unsigned short*)(w + 24 * MB);
  unsigned short* bfc1  = (unsigned short*)(w + 32 * MB);
  unsigned short* qhb   = (unsigned short*)(w + 40 * MB);
  unsigned short* khb   = (unsigned short*)(w + 56 * MB);
  unsigned short* vtb   = (unsigned short*)(w + 72 * MB);
  unsigned short* attnb = (unsigned short*)(w + 88 * MB);
  unsigned short* qkvb  = (unsigned short*)(w + 104 * MB);
  unsigned short* midb  = (unsigned short*)(w + 104 * MB);  // alias, qkvb dead by then

  castw_kernel<<<3072, 256, 0, stream>>>(wqkv, bqkv, 786432);
  castw_kernel<<<1024, 256, 0, stream>>>(wo, bwo, 262144);
  castw_kernel<<<4096, 256, 0, stream>>>(fc0w, bfc0, 1048576);
  castw_kernel<<<4096, 256, 0, stream>>>(fc1w, bfc1, 1048576);
  ln_kernel<<<8192, 256, 0, stream>>>(x, ln0g, ln0b, hb);
  gemm_bt<4><<<dim3(24, 64), 256, 0, stream>>>(hb, bqkv, 8192, 3072, 1024,
                                               nullptr, qkvb, nullptr, nullptr);
  rope_kernel<<<16384, 256, 0, stream>>>(qkvb, rc, rsn, qhb, khb);
  vtrans_kernel<<<2048, 256, 0, stream>>>(qkvb, vtb);
  attn_kernel<<<1024, 256, 0, stream>>>(qhb, khb, vtb, attnb);
  gemm_bt<1><<<dim3(8, 64), 256, 0, stream>>>(attnb, bwo, 8192, 1024, 1024,
                                              out, nullptr, x, nullptr);
  ln_kernel<<<8192, 256, 0, stream>>>(out, ln1g, ln1b, hb);
  gemm_bt<2><<<dim3(32, 64), 256, 0, stream>>>(hb, bfc0, 8192, 4096, 1024,
                                               nullptr, midb, nullptr, fc0b);
  gemm_bt<3><<<dim3(8, 64), 256, 0, stream>>>(midb, bfc1, 8192, 1024, 4096,
                                              out, nullptr, out, fc1b);
}

// Round 3
// 545.723 us; speedup vs baseline: 1.1667x; 1.0315x over previous
//
#include <hip/hip_runtime.h>
#include <math.h>

// ---------------------------------------------------------------------------
// VideoChat3 vision encoder block, bf16-MFMA pipeline. Round 3:
//  - FC0 epilogue: erf-GELU -> exp2-based tanh-GELU (1 transcendental)
//  - attention on 32x32x16 MFMA, S^T trick + in-register P transpose
//    (no Ps LDS round-trip, 32KB LDS, shfl_xor(32) half-wave exchange)
//  - fused weight-cast kernel, vectorized RoPE
// S=8192, H=1024, NH=16, HD=64, NSEG=8, L=1024, MLP=4096.
// ---------------------------------------------------------------------------

typedef __bf16 bf16x8 __attribute__((ext_vector_type(8)));
typedef float f32x4 __attribute__((ext_vector_type(4)));
typedef float f32x16 __attribute__((ext_vector_type(16)));
typedef unsigned int u32;

__device__ __forceinline__ unsigned short f2b(float f) {  // RNE f32->bf16
  unsigned u = __float_as_uint(f);
  return (unsigned short)((u + 0x7FFFu + ((u >> 16) & 1u)) >> 16);
}
__device__ __forceinline__ float b2f(unsigned short h) {
  return __uint_as_float(((unsigned)h) << 16);
}
__device__ __forceinline__ void async_ld16(const void* g, void* l) {
  __builtin_amdgcn_global_load_lds((__attribute__((address_space(1))) void*)g,
                                   (__attribute__((address_space(3))) void*)l,
                                   16, 0, 0);
}
__device__ __forceinline__ float exp2fast(float x) {
#if __has_builtin(__builtin_amdgcn_exp2f)
  return __builtin_amdgcn_exp2f(x);
#else
  return exp2f(x);
#endif
}
__device__ __forceinline__ float rcpfast(float x) {
#if __has_builtin(__builtin_amdgcn_rcpf)
  return __builtin_amdgcn_rcpf(x);
#else
  return 1.0f / x;
#endif
}

// ---------------- fused weight cast fp32 -> bf16 ---------------------------
// dst = contiguous [bqkv | bwo | bfc0 | bfc1] region (ws +16MB..+40MB)
__global__ __launch_bounds__(256) void castall_kernel(
    const float* __restrict__ s0, const float* __restrict__ s1,
    const float* __restrict__ s2, const float* __restrict__ s3,
    unsigned short* __restrict__ dst) {
  const int t = blockIdx.x * 256 + threadIdx.x;  // 0..3145727 float4 groups
  const float* src;
  int off;
  if (t < 786432) { src = s0; off = t; }
  else if (t < 1048576) { src = s1; off = t - 786432; }
  else if (t < 2097152) { src = s2; off = t - 1048576; }
  else { src = s3; off = t - 2097152; }
  const float4 v = ((const float4*)src)[off];
  ushort4 o;
  o.x = f2b(v.x); o.y = f2b(v.y); o.z = f2b(v.z); o.w = f2b(v.w);
  ((ushort4*)dst)[t] = o;
}

// ---------------- layernorm (row of 1024) -> bf16 --------------------------
__global__ __launch_bounds__(256) void ln_kernel(const float* __restrict__ x,
                                                 const float* __restrict__ g,
                                                 const float* __restrict__ bt,
                                                 unsigned short* __restrict__ out) {
  __shared__ float red[8];
  const int row = blockIdx.x, t = threadIdx.x;
  const float4 v = ((const float4*)(x + (size_t)row * 1024))[t];
  float s = v.x + v.y + v.z + v.w;
  float s2 = v.x * v.x + v.y * v.y + v.z * v.z + v.w * v.w;
#pragma unroll
  for (int m = 1; m < 64; m <<= 1) {
    s += __shfl_xor(s, m, 64);
    s2 += __shfl_xor(s2, m, 64);
  }
  if ((t & 63) == 0) { red[t >> 6] = s; red[4 + (t >> 6)] = s2; }
  __syncthreads();
  const float ts = red[0] + red[1] + red[2] + red[3];
  const float ts2 = red[4] + red[5] + red[6] + red[7];
  const float mean = ts * (1.f / 1024.f);
  const float var = ts2 * (1.f / 1024.f) - mean * mean;
  const float inv = rsqrtf(var + 1e-5f);
  const float4 gv = ((const float4*)g)[t];
  const float4 bv = ((const float4*)bt)[t];
  ushort4 o;
  o.x = f2b((v.x - mean) * inv * gv.x + bv.x);
  o.y = f2b((v.y - mean) * inv * gv.y + bv.y);
  o.z = f2b((v.z - mean) * inv * gv.z + bv.z);
  o.w = f2b((v.w - mean) * inv * gv.w + bv.w);
  ((ushort4*)out)[(size_t)row * 256 + t] = o;
}

// ---------------- GEMM: C[M,N] = A[M,K] @ B[N,K]^T, bf16 in, fp32 acc ------
// 128x128 tile, 4 waves, 16x16x32 MFMA, XOR-swizzled LDS (conflict-free).
template <int MODE>
__global__ __launch_bounds__(256) void gemm_bt(
    const unsigned short* __restrict__ A, const unsigned short* __restrict__ B,
    int M, int N, int K, float* __restrict__ outf, unsigned short* __restrict__ outb,
    const float* __restrict__ res, const float* __restrict__ bias) {
  __shared__ __align__(16) unsigned short As[128 * 32];
  __shared__ __align__(16) unsigned short Bs[128 * 32];
  const int bm = blockIdx.y * 128, bn = blockIdx.x * 128;
  const int t = threadIdx.x, wave = t >> 6, lane = t & 63;
  const int quad = lane >> 4, l16 = lane & 15;
  const int wm = (wave >> 1) * 64, wn = (wave & 1) * 64;
  const int srow = lane >> 2;
  const int scol = (((lane & 3) ^ ((lane >> 3) & 3)) * 8);  // swizzled source col
  const unsigned short* Ag0 = A + (size_t)(bm + wave * 32 + srow) * K + scol;
  const unsigned short* Ag1 = Ag0 + (size_t)16 * K;
  const unsigned short* Bg0 = B + (size_t)(bn + wave * 32 + srow) * K + scol;
  const unsigned short* Bg1 = Bg0 + (size_t)16 * K;
  unsigned short* Al = As + wave * 1024;
  unsigned short* Bl = Bs + wave * 1024;
  const int swg = (l16 >> 1) & 3;  // read-side swizzle key
  f32x4 acc[4][4] = {};
  for (int k0 = 0; k0 < K; k0 += 32) {
    async_ld16(Ag0 + k0, Al);
    async_ld16(Ag1 + k0, Al + 512);
    async_ld16(Bg0 + k0, Bl);
    async_ld16(Bg1 + k0, Bl + 512);
    __syncthreads();
    bf16x8 af[4], bfv[4];
#pragma unroll
    for (int i = 0; i < 4; i++)
      af[i] = *(const bf16x8*)(As + (wm + i * 16 + l16) * 32 + (quad ^ swg) * 8);
#pragma unroll
    for (int j = 0; j < 4; j++)
      bfv[j] = *(const bf16x8*)(Bs + (wn + j * 16 + l16) * 32 + (quad ^ swg) * 8);
#pragma unroll
    for (int i = 0; i < 4; i++)
#pragma unroll
      for (int j = 0; j < 4; j++)
        acc[i][j] = __builtin_amdgcn_mfma_f32_16x16x32_bf16(af[i], bfv[j], acc[i][j], 0, 0, 0);
    __syncthreads();
  }
#pragma unroll
  for (int i = 0; i < 4; i++)
#pragma unroll
    for (int j = 0; j < 4; j++)
#pragma unroll
      for (int r = 0; r < 4; r++) {
        const int m = bm + wm + i * 16 + quad * 4 + r;
        const int n = bn + wn + j * 16 + l16;
        const size_t idx = (size_t)m * N + n;
        const float v = acc[i][j][r];
        if (MODE == 1) {
          outf[idx] = v + res[idx];
        } else if (MODE == 2) {
          // tanh-GELU via native exp2: g = z*t/(t+1), t = exp2(2.88539*u)
          const float z = v + bias[n];
          const float u = z * (0.7978845608f + 0.03567740814f * z * z);
          const float e = fminf(u * 2.885390082f, 80.f);
          const float tt = exp2fast(e);
          outb[idx] = f2b(z * tt * rcpfast(tt + 1.0f));
        } else if (MODE == 3) {
          outf[idx] = v + bias[n] + res[idx];
        } else {  // MODE 4
          outb[idx] = f2b(v);
        }
      }
}

// ---------------- RoPE: qkv(bf16,[S,3,NH,HD]) -> qh,kh ([seg,NH,L,HD]) -----
// 8 shorts (4 rotation pairs) per thread. q pre-scale folds 1/8 and log2e.
__device__ __forceinline__ u32 rope2(u32 in, float c, float sn, float sc) {
  const float a = b2f((unsigned short)(in & 0xffff));
  const float b = b2f((unsigned short)(in >> 16));
  return (u32)f2b((a * c - b * sn) * sc) | ((u32)f2b((a * sn + b * c) * sc) << 16);
}
__global__ __launch_bounds__(256) void rope_kernel(const unsigned short* __restrict__ qkv,
                                                   const float* __restrict__ cb,
                                                   const float* __restrict__ sb,
                                                   unsigned short* __restrict__ qh,
                                                   unsigned short* __restrict__ kh) {
  const int tid = blockIdx.x * 256 + threadIdx.x;  // S*NH*8 threads
  const int ii = tid & 7, head = (tid >> 3) & 15, s = tid >> 7;
  const float4 cv = *(const float4*)(cb + s * 32 + ii * 4);
  const float4 sv = *(const float4*)(sb + s * 32 + ii * 4);
  const unsigned short* base = qkv + (size_t)s * 3072 + head * 64 + ii * 8;
  const uint4 qa = *(const uint4*)base;
  const uint4 ka = *(const uint4*)(base + 1024);
  const int seg = s >> 10, l = s & 1023;
  const size_t o = ((size_t)((seg * 16 + head) * 1024 + l)) * 64 + ii * 8;
  const float QSC = 0.125f * 1.44269504f;
  uint4 qo, ko;
  qo.x = rope2(qa.x, cv.x, sv.x, QSC); ko.x = rope2(ka.x, cv.x, sv.x, 1.f);
  qo.y = rope2(qa.y, cv.y, sv.y, QSC); ko.y = rope2(ka.y, cv.y, sv.y, 1.f);
  qo.z = rope2(qa.z, cv.z, sv.z, QSC); ko.z = rope2(ka.z, cv.z, sv.z, 1.f);
  qo.w = rope2(qa.w, cv.w, sv.w, QSC); ko.w = rope2(ka.w, cv.w, sv.w, 1.f);
  *(uint4*)(qh + o) = qo;
  *(uint4*)(kh + o) = ko;
}

// ---------------- V transpose: qkv v-part -> vt [seg,NH,HD,L] --------------
__global__ __launch_bounds__(256) void vtrans_kernel(const unsigned short* __restrict__ qkv,
                                                     unsigned short* __restrict__ vt) {
  __shared__ unsigned short tile[64][72];
  const int b = blockIdx.x;  // 8*16*16
  const int lt = b & 15, head = (b >> 4) & 15, seg = b >> 8;
  const int t = threadIdx.x;
  const int r = t >> 2, c0 = (t & 3) * 16;
  const unsigned short* src =
      qkv + ((size_t)(seg * 1024 + lt * 64 + r)) * 3072 + 2048 + head * 64 + c0;
#pragma unroll
  for (int k = 0; k < 16; k++) tile[r][c0 + k] = src[k];
  __syncthreads();
  unsigned short* dst =
      vt + ((size_t)((seg * 16 + head) * 64 + r)) * 1024 + lt * 64 + c0;
#pragma unroll
  for (int k = 0; k < 16; k++) dst[k] = tile[c0 + k][r];
}

// ---------------- flash attention, 32x32x16 MFMA, in-register P ------------
// Per block: 128 queries x (seg,head); per wave: 32 queries (lane&31 = query).
// S^T = K.Q^T so C-layout puts query on lane&31; P transposed to PV A-layout
// via one half-wave shfl_xor(32) exchange of packed bf16 pairs. No Ps LDS.
__global__ __launch_bounds__(256) void attn_kernel(const unsigned short* __restrict__ qh,
                                                   const unsigned short* __restrict__ kh,
                                                   const unsigned short* __restrict__ vt,
                                                   unsigned short* __restrict__ out) {
  __shared__ __align__(16) unsigned short Qs[128 * 64];
  __shared__ __align__(16) unsigned short Ks[64 * 64];
  __shared__ __align__(16) unsigned short Vs[64 * 64];  // [hd][key]
  __shared__ float wl[128];
  const int b = blockIdx.x;
  const int head = b & 15, seg = (b >> 4) & 7, qt = b >> 7;
  const int t = threadIdx.x, wave = t >> 6, lane = t & 63;
  const int h = lane >> 5, q31 = lane & 31;
  const size_t sh = (size_t)(seg * 16 + head);
  const unsigned short* qbase = qh + (sh * 1024 + (size_t)qt * 128) * 64;
  const unsigned short* kbase = kh + sh * 1024 * 64;
  const unsigned short* vbase = vt + sh * 64 * 1024;
  const int r8 = lane >> 3;
  const int c8 = ((lane & 7) ^ (r8 & 7)) * 8;  // swizzled source col (shorts)
#pragma unroll
  for (int cc = 0; cc < 4; cc++) {  // stage Q once (16KB, 16 chunks)
    const int chunk = wave * 4 + cc;
    async_ld16(qbase + (size_t)(chunk * 8 + r8) * 64 + c8, Qs + chunk * 512);
  }
  const int qrow_l = wave * 32 + q31;          // this lane's query row in tile
  const int qsw = qrow_l & 7;                  // Qs swizzle key
  bf16x8 qf[4];                                // Q B-frags, loaded once
  float lsum = 0.f;
  f32x16 oacc[2] = {};

  for (int kt = 0; kt < 16; kt++) {
    const int ch0 = wave * 2;
    async_ld16(kbase + (size_t)(kt * 64 + ch0 * 8 + r8) * 64 + c8, Ks + ch0 * 512);
    async_ld16(kbase + (size_t)(kt * 64 + ch0 * 8 + 8 + r8) * 64 + c8, Ks + ch0 * 512 + 512);
    async_ld16(vbase + (size_t)(ch0 * 8 + r8) * 1024 + kt * 64 + c8, Vs + ch0 * 512);
    async_ld16(vbase + (size_t)(ch0 * 8 + 8 + r8) * 1024 + kt * 64 + c8, Vs + ch0 * 512 + 512);
    __syncthreads();
    if (kt == 0) {
#pragma unroll
      for (int ks = 0; ks < 4; ks++)
        qf[ks] = *(const bf16x8*)(Qs + qrow_l * 64 + (((2 * ks + h) ^ qsw)) * 8);
    }
    // S^T = K.Q^T : 2 key tiles x 4 ksteps
    f32x16 st[2] = {{}, {}};
#pragma unroll
    for (int T = 0; T < 2; T++) {
      const int krow = 32 * T + q31;
      const int ksw = krow & 7;
#pragma unroll
      for (int ks = 0; ks < 4; ks++) {
        const bf16x8 kf = *(const bf16x8*)(Ks + krow * 64 + (((2 * ks + h) ^ ksw)) * 8);
        st[T] = __builtin_amdgcn_mfma_f32_32x32x16_bf16(kf, qf[ks], st[T], 0, 0, 0);
      }
    }
    // p = exp2(s) (q pre-scaled by log2e/8); pack bf16 pairs per group
    u32 pk[2][4][2];
#pragma unroll
    for (int T = 0; T < 2; T++)
#pragma unroll
      for (int g = 0; g < 4; g++)
#pragma unroll
        for (int e = 0; e < 2; e++) {
          const float plo = exp2fast(st[T][4 * g + 2 * e]);
          const float phi = exp2fast(st[T][4 * g + 2 * e + 1]);
          lsum += plo + phi;
          pk[T][g][e] = (u32)f2b(plo) | ((u32)f2b(phi) << 16);
        }
    // half-wave exchange: h=0 sends g1,g3 / receives partner's g0,g2;
    //                     h=1 sends g0,g2 / receives partner's g1,g3
    u32 rcv[2][4];
#pragma unroll
    for (int T = 0; T < 2; T++) {
      const u32 p0 = h ? pk[T][0][0] : pk[T][1][0];
      const u32 p1 = h ? pk[T][0][1] : pk[T][1][1];
      const u32 p2 = h ? pk[T][2][0] : pk[T][3][0];
      const u32 p3 = h ? pk[T][2][1] : pk[T][3][1];
      rcv[T][0] = (u32)__shfl_xor((int)p0, 32, 64);
      rcv[T][1] = (u32)__shfl_xor((int)p1, 32, 64);
      rcv[T][2] = (u32)__shfl_xor((int)p2, 32, 64);
      rcv[T][3] = (u32)__shfl_xor((int)p3, 32, 64);
    }
    // O += P.V : A-frag[t] assembled in-register; B from Vs[hd][key]
#pragma unroll
    for (int tt = 0; tt < 4; tt++) {
      const int T = tt >> 1, uu = tt & 1;
      union { u32 u[4]; bf16x8 v; } af;
      if (h == 0) {
        af.u[0] = pk[T][2 * uu][0];
        af.u[1] = pk[T][2 * uu][1];
        af.u[2] = rcv[T][2 * uu];
        af.u[3] = rcv[T][2 * uu + 1];
      } else {
        af.u[0] = rcv[T][2 * uu];
        af.u[1] = rcv[T][2 * uu + 1];
        af.u[2] = pk[T][2 * uu + 1][0];
        af.u[3] = pk[T][2 * uu + 1][1];
      }
#pragma unroll
      for (int ot = 0; ot < 2; ot++) {
        const int vrow = 32 * ot + q31;
        const int vsw = vrow & 7;
        const bf16x8 bv = *(const bf16x8*)(Vs + vrow * 64 + (((2 * tt + h) ^ vsw)) * 8);
        oacc[ot] = __builtin_amdgcn_mfma_f32_32x32x16_bf16(af.v, bv, oacc[ot], 0, 0, 0);
      }
    }
    __syncthreads();
  }
  // epilogue: full row-sum (other 32 keys live in lane^32), normalize, store
  lsum += __shfl_xor(lsum, 32, 64);
  if (h == 0) wl[wave * 32 + q31] = lsum;
  const int qglob = seg * 1024 + qt * 128 + wave * 32;
#pragma unroll
  for (int g = 0; g < 4; g++) {
    const float4 lv = *(const float4*)&wl[wave * 32 + 8 * g + 4 * h];
#pragma unroll
    for (int m = 0; m < 4; m++) {
      const int r16 = 4 * g + m;
      const int qrow = qglob + m + 8 * g + 4 * h;
      const float invl = rcpfast((&lv.x)[m]);
#pragma unroll
      for (int ot = 0; ot < 2; ot++)
        out[(size_t)qrow * 1024 + head * 64 + 32 * ot + q31] = f2b(oacc[ot][r16] * invl);
    }
  }
}

// ---------------------------------------------------------------------------
extern "C" void kernel_launch(void* const* d_in, const int* in_sizes, int n_in,
                              void* d_out, int out_size, void* d_ws, size_t ws_size,
                              hipStream_t stream) {
  (void)in_sizes; (void)n_in; (void)out_size; (void)ws_size;
  const float* x    = (const float*)d_in[0];
  const float* wqkv = (const float*)d_in[1];
  const float* wo   = (const float*)d_in[2];
  const float* ln0g = (const float*)d_in[3];
  const float* ln0b = (const float*)d_in[4];
  const float* ln1g = (const float*)d_in[5];
  const float* ln1b = (const float*)d_in[6];
  const float* fc0w = (const float*)d_in[7];
  const float* fc0b = (const float*)d_in[8];
  const float* fc1w = (const float*)d_in[9];
  const float* fc1b = (const float*)d_in[10];
  const float* rc   = (const float*)d_in[11];
  const float* rsn  = (const float*)d_in[12];
  float* out = (float*)d_out;
  char* w = (char*)d_ws;
  const size_t MB = 1u << 20;
  unsigned short* hb    = (unsigned short*)(w + 0);
  unsigned short* bqkv  = (unsigned short*)(w + 16 * MB);
  unsigned short* bwo   = (unsigned short*)(w + 22 * MB);
  unsigned short* bfc0  = (unsigned short*)(w + 24 * MB);
  unsigned short* bfc1  = (unsigned short*)(w + 32 * MB);
  unsigned short* qhb   = (unsigned short*)(w + 40 * MB);
  unsigned short* khb   = (unsigned short*)(w + 56 * MB);
  unsigned short* vtb   = (unsigned short*)(w + 72 * MB);
  unsigned short* attnb = (unsigned short*)(w + 88 * MB);
  unsigned short* qkvb  = (unsigned short*)(w + 104 * MB);
  unsigned short* midb  = (unsigned short*)(w + 104 * MB);  // alias, qkvb dead by then

  castall_kernel<<<12288, 256, 0, stream>>>(wqkv, wo, fc0w, fc1w, bqkv);
  ln_kernel<<<8192, 256, 0, stream>>>(x, ln0g, ln0b, hb);
  gemm_bt<4><<<dim3(24, 64), 256, 0, stream>>>(hb, bqkv, 8192, 3072, 1024,
                                               nullptr, qkvb, nullptr, nullptr);
  rope_kernel<<<4096, 256, 0, stream>>>(qkvb, rc, rsn, qhb, khb);
  vtrans_kernel<<<2048, 256, 0, stream>>>(qkvb, vtb);
  attn_kernel<<<1024, 256, 0, stream>>>(qhb, khb, vtb, attnb);
  gemm_bt<1><<<dim3(8, 64), 256, 0, stream>>>(attnb, bwo, 8192, 1024, 1024,
                                              out, nullptr, x, nullptr);
  ln_kernel<<<8192, 256, 0, stream>>>(out, ln1g, ln1b, hb);
  gemm_bt<2><<<dim3(32, 64), 256, 0, stream>>>(hb, bfc0, 8192, 4096, 1024,
                                               nullptr, midb, nullptr, fc0b);
  gemm_bt<3><<<dim3(8, 64), 256, 0, stream>>>(midb, bfc1, 8192, 1024, 4096,
                                              out, nullptr, out, fc1b);
}